// Round 5
// baseline (299.361 us; speedup 1.0000x reference)
//
#include <hip/hip_runtime.h>
#include <stdint.h>

typedef unsigned int  u32;
typedef unsigned short u16;
typedef __bf16 bf16x8 __attribute__((ext_vector_type(8)));
typedef float  f32x4  __attribute__((ext_vector_type(4)));

// db4 correlation filters (pywt dec_lo/dec_hi reversed), matching lax.conv
__constant__ float GL[8] = { 0.23037781330885523f,  0.7148465705525415f,
                             0.6308807679295904f,  -0.02798376941698385f,
                            -0.18703481171888114f,  0.030841381835986965f,
                             0.032883011666982945f,-0.010597401784997278f };
__constant__ float GH[8] = {-0.010597401784997278f,-0.032883011666982945f,
                             0.030841381835986965f, 0.18703481171888114f,
                            -0.02798376941698385f, -0.6308807679295904f,
                             0.7148465705525415f,  -0.23037781330885523f };

__device__ inline u16 f32_bf16(float f) {
    u32 u = __float_as_uint(f);
    u += 0x7fffu + ((u >> 16) & 1u);
    return (u16)(u >> 16);
}
__device__ inline u32 pack2_bf16(float a, float b) {
    u32 ua = __float_as_uint(a); ua += 0x7fffu + ((ua >> 16) & 1u);
    u32 ub = __float_as_uint(b); ub += 0x7fffu + ((ub >> 16) & 1u);
    return (ua >> 16) | (ub & 0xffff0000u);
}

// ---------------------------------------------------------------------------
// Kernel 1: fold DWT into conv weights, no LDS, no barriers.
// Every thread builds the full DWT column Wd[tau][t] for its OWN t = lane
// (84 registers), then loops tau with WAVE-UNIFORM scalar loads of cw.
// Thread (t = lane, wave w) produces Wp[n][t*64 + hw] for hw in
// [w*16, w*16+16), emitted directly in MFMA B-fragment order as two 16B
// stores:  Wf[(((s*8+nt)*128 + kb)*64 + fq*16 + fr)*8 + jj]
//   kb = t*2 + (hw>>5), fq = (hw>>3)&3, jj = hw&7, nt = n>>4, fr = n&15.
// One block per (s,n).  Wd order: lo3(14) | hi1(35) | hi2(21) | hi3(14).
// ---------------------------------------------------------------------------
__global__ __launch_bounds__(256) void fold_w(const float* __restrict__ cw,
                                              u16* __restrict__ Wf) {
    const int tid = threadIdx.x;
    const int t   = tid & 63;                     // time index = lane
    const int wq  = __builtin_amdgcn_readfirstlane((int)(tid >> 6)); // wave 0..3

    // ---- build Wd[·][t] in registers (j = t is this lane's basis index) ----
    float wd[84], lo1[35], lo2[21];
#pragma unroll
    for (int i = 0; i < 35; ++i) {                // level 1: N=64, reflect 6
        float sl = 0.f, sh = 0.f;
#pragma unroll
        for (int k = 0; k < 8; ++k) {
            int s = 2 * i + k - 6;
            if (s < 0) s = -s;
            if (s >= 64) s = 126 - s;
            float xv = (s == t) ? 1.0f : 0.0f;
            sl += xv * GL[k]; sh += xv * GH[k];
        }
        lo1[i] = sl;
        wd[14 + i] = sh;
    }
#pragma unroll
    for (int i = 0; i < 21; ++i) {                // level 2: N=35 (+1 zero)
        float sl = 0.f, sh = 0.f;
#pragma unroll
        for (int k = 0; k < 8; ++k) {
            int s = 2 * i + k - 6;
            if (s < 0) s = -s;
            if (s >= 36) s = 70 - s;
            float xv = (s >= 35) ? 0.0f : lo1[s];
            sl += xv * GL[k]; sh += xv * GH[k];
        }
        lo2[i] = sl;
        wd[49 + i] = sh;
    }
#pragma unroll
    for (int i = 0; i < 14; ++i) {                // level 3: N=21 (+1 zero)
        float sl = 0.f, sh = 0.f;
#pragma unroll
        for (int k = 0; k < 8; ++k) {
            int s = 2 * i + k - 6;
            if (s < 0) s = -s;
            if (s >= 22) s = 42 - s;
            float xv = (s >= 21) ? 0.0f : lo2[s];
            sl += xv * GL[k]; sh += xv * GH[k];
        }
        wd[i] = sl;
        wd[70 + i] = sh;
    }

    // ---- fold: acc[j] = sum_tau cw[s,n,tau, w*16+j] * wd[tau] ----
    const int sk = blockIdx.x;                    // s*128 + n
    const float* cwp = cw + (size_t)sk * (84 * 64) + wq * 16;  // wave-uniform
    float acc[16];
#pragma unroll
    for (int j = 0; j < 16; ++j) acc[j] = 0.f;
#pragma unroll
    for (int tau = 0; tau < 84; ++tau) {
#pragma unroll
        for (int j = 0; j < 16; ++j)
            acc[j] += cwp[tau * 64 + j] * wd[tau];   // cwp[..] is s_load
    }

    // ---- emit in B-fragment order, two 16B stores ----
    const int s  = sk >> 7;
    const int n  = sk & 127;
    const int nt = n >> 4;
    const int fr = n & 15;
#pragma unroll
    for (int h8 = 0; h8 < 2; ++h8) {
        const int hw0 = wq * 16 + h8 * 8;
        const int kb  = t * 2 + (hw0 >> 5);
        const int fq  = (hw0 >> 3) & 3;
        union { u16 h[8]; u32 w2[4]; } pk;
#pragma unroll
        for (int j = 0; j < 8; ++j) pk.h[j] = f32_bf16(acc[h8 * 8 + j]);
        const size_t idx =
            ((((size_t)(s * 8 + nt)) * 128 + kb) * 64 + fq * 16 + fr) * 8;
        *reinterpret_cast<u32*>(&Wf[idx])     = pk.w2[0];
        *reinterpret_cast<u32*>(&Wf[idx + 2]) = pk.w2[1];
        *reinterpret_cast<u32*>(&Wf[idx + 4]) = pk.w2[2];
        *reinterpret_cast<u32*>(&Wf[idx + 6]) = pk.w2[3];
    }
}

// ---------------------------------------------------------------------------
// Kernel 2: barrier-free, LDS-free MFMA GEMM with K-split, 32 m-rows/wave.
// wave gw: ksid = gw>>8, s = (gw>>6)&3, mt = gw&63 computes a 32(m) x 128(n)
// partial tile over K-slice [ksid*NKB*32, (ksid+1)*NKB*32).  Each B fragment
// feeds TWO MFMAs (halves L2 B-traffic).  A from global fp32 -> bf16 pack.
// ---------------------------------------------------------------------------
template <int NKB>
__global__ __launch_bounds__(256, 2) void gemm3(const float* __restrict__ X,
                                                const u16* __restrict__ Wf,
                                                float* __restrict__ P) {
    const int tid  = threadIdx.x;
    const int lane = tid & 63;
    const int gw   = blockIdx.x * 4 + (tid >> 6);
    const int ksid = gw >> 8;          // K-slice id
    const int s    = (gw >> 6) & 3;    // subwindow
    const int mt   = gw & 63;          // m-tile (32 rows)
    const int fr   = lane & 15;
    const int fq   = lane >> 4;
    const int kb0  = ksid * NKB;

    const float* xg0 = X + (size_t)(mt * 32 + fr) * 16384 + s * 4096 + kb0 * 32 + fq * 8;
    const float* xg1 = xg0 + (size_t)16 * 16384;
    const u16*   wg  = Wf + (((size_t)(s * 8) * 128) + kb0) * 512 + lane * 8;
    // strides (u16): nt -> 65536 ; kb -> 512

    f32x4 acc0[8], acc1[8];
#pragma unroll
    for (int nt = 0; nt < 8; ++nt) {
        acc0[nt] = (f32x4){0.f, 0.f, 0.f, 0.f};
        acc1[nt] = (f32x4){0.f, 0.f, 0.f, 0.f};
    }

    // prefetch A for kb=0
    f32x4 a0 = __builtin_nontemporal_load(reinterpret_cast<const f32x4*>(xg0));
    f32x4 a1 = __builtin_nontemporal_load(reinterpret_cast<const f32x4*>(xg0) + 1);
    f32x4 a2 = __builtin_nontemporal_load(reinterpret_cast<const f32x4*>(xg1));
    f32x4 a3 = __builtin_nontemporal_load(reinterpret_cast<const f32x4*>(xg1) + 1);

#pragma unroll 2
    for (int kb = 0; kb < NKB; ++kb) {
        union { u32 u[4]; bf16x8 v; } av0, av1;
        av0.u[0] = pack2_bf16(a0.x, a0.y); av0.u[1] = pack2_bf16(a0.z, a0.w);
        av0.u[2] = pack2_bf16(a1.x, a1.y); av0.u[3] = pack2_bf16(a1.z, a1.w);
        av1.u[0] = pack2_bf16(a2.x, a2.y); av1.u[1] = pack2_bf16(a2.z, a2.w);
        av1.u[2] = pack2_bf16(a3.x, a3.y); av1.u[3] = pack2_bf16(a3.z, a3.w);
        // prefetch next (clamped; redundant last reload harmless)
        const int kn = (kb + 1 < NKB) ? kb + 1 : kb;
        a0 = __builtin_nontemporal_load(reinterpret_cast<const f32x4*>(xg0 + (size_t)kn * 32));
        a1 = __builtin_nontemporal_load(reinterpret_cast<const f32x4*>(xg0 + (size_t)kn * 32) + 1);
        a2 = __builtin_nontemporal_load(reinterpret_cast<const f32x4*>(xg1 + (size_t)kn * 32));
        a3 = __builtin_nontemporal_load(reinterpret_cast<const f32x4*>(xg1 + (size_t)kn * 32) + 1);
        const u16* wb = wg + (size_t)kb * 512;
#pragma unroll
        for (int nt = 0; nt < 8; ++nt) {
            bf16x8 bf = *reinterpret_cast<const bf16x8*>(wb + (size_t)nt * 65536);
            acc0[nt] = __builtin_amdgcn_mfma_f32_16x16x32_bf16(av0.v, bf, acc0[nt], 0, 0, 0);
            acc1[nt] = __builtin_amdgcn_mfma_f32_16x16x32_bf16(av1.v, bf, acc1[nt], 0, 0, 0);
        }
    }

    // partials: P[ksid][mt*32 + (0|16) + fq*4 + r][s*128 + nt*16 + fr]
    float* pg = P + (size_t)ksid * (2048 * 512) + (size_t)(mt * 32) * 512 + s * 128 + fr;
#pragma unroll
    for (int nt = 0; nt < 8; ++nt)
#pragma unroll
        for (int r = 0; r < 4; ++r) {
            __builtin_nontemporal_store(acc0[nt][r], pg + (size_t)(fq * 4 + r) * 512 + nt * 16);
            __builtin_nontemporal_store(acc1[nt][r], pg + (size_t)(16 + fq * 4 + r) * 512 + nt * 16);
        }
}

// ---------------------------------------------------------------------------
// Kernel 3: reduce K-slices, add bias, leaky-ReLU.
// ---------------------------------------------------------------------------
__global__ __launch_bounds__(256) void reduce_k(const float* __restrict__ P,
                                                const float* __restrict__ bias,
                                                float* __restrict__ out, int nks) {
    const int t = blockIdx.x * 256 + threadIdx.x;     // 0..262143
    const size_t base = (size_t)t * 4;
    f32x4 sum = {0.f, 0.f, 0.f, 0.f};
    for (int k = 0; k < nks; ++k) {
        f32x4 v = __builtin_nontemporal_load(
            reinterpret_cast<const f32x4*>(P + (size_t)k * (2048 * 512) + base));
        sum += v;
    }
    const f32x4 b = *reinterpret_cast<const f32x4*>(bias + (base & 511));
    f32x4 o = sum + b;
    o.x = o.x > 0.f ? o.x : 0.01f * o.x;
    o.y = o.y > 0.f ? o.y : 0.01f * o.y;
    o.z = o.z > 0.f ? o.z : 0.01f * o.z;
    o.w = o.w > 0.f ? o.w : 0.01f * o.w;
    __builtin_nontemporal_store(o, reinterpret_cast<f32x4*>(out + base));
}

// ---------------------------------------------------------------------------
extern "C" void kernel_launch(void* const* d_in, const int* in_sizes, int n_in,
                              void* d_out, int out_size, void* d_ws, size_t ws_size,
                              hipStream_t stream) {
    const float* x  = (const float*)d_in[0];   // [2048,1,256,8,8] fp32
    const float* cw = (const float*)d_in[1];   // [4,128,84,8,8]   fp32
    const float* cb = (const float*)d_in[2];   // [4,128]          fp32
    float* out = (float*)d_out;                // [2048,512]       fp32

    u16*   Wf = (u16*)d_ws;                              // 4 MiB, B-fragment order
    float* P  = (float*)((char*)d_ws + (4u << 20));      // KS * 4 MiB partials

    const size_t MN = (size_t)2048 * 512 * 4;            // 4 MiB per K-slice
    int ks = (ws_size >= (4u << 20) + 8 * MN) ? 8
           : (ws_size >= (4u << 20) + 4 * MN) ? 4
           : (ws_size >= (4u << 20) + 2 * MN) ? 2 : 1;

    fold_w<<<512, 256, 0, stream>>>(cw, Wf);
    switch (ks) {
        case 8: gemm3<16> <<<8 * 64, 256, 0, stream>>>(x, Wf, P); break;
        case 4: gemm3<32> <<<4 * 64, 256, 0, stream>>>(x, Wf, P); break;
        case 2: gemm3<64> <<<2 * 64, 256, 0, stream>>>(x, Wf, P); break;
        default: gemm3<128><<<1 * 64, 256, 0, stream>>>(x, Wf, P); break;
    }
    reduce_k<<<1024, 256, 0, stream>>>(P, cb, out, ks);
}

// Round 7
// 297.677 us; speedup vs baseline: 1.0057x; 1.0057x over previous
//
#include <hip/hip_runtime.h>
#include <stdint.h>

typedef unsigned int  u32;
typedef unsigned short u16;
typedef __bf16 bf16x8 __attribute__((ext_vector_type(8)));
typedef float  f32x4  __attribute__((ext_vector_type(4)));

// db4 correlation filters (pywt dec_lo/dec_hi reversed), matching lax.conv
__constant__ float GL[8] = { 0.23037781330885523f,  0.7148465705525415f,
                             0.6308807679295904f,  -0.02798376941698385f,
                            -0.18703481171888114f,  0.030841381835986965f,
                             0.032883011666982945f,-0.010597401784997278f };
__constant__ float GH[8] = {-0.010597401784997278f,-0.032883011666982945f,
                             0.030841381835986965f, 0.18703481171888114f,
                            -0.02798376941698385f, -0.6308807679295904f,
                             0.7148465705525415f,  -0.23037781330885523f };

__device__ inline u16 f32_bf16(float f) {
    u32 u = __float_as_uint(f);
    u += 0x7fffu + ((u >> 16) & 1u);
    return (u16)(u >> 16);
}
__device__ inline u32 pack2_bf16(float a, float b) {
    u32 ua = __float_as_uint(a); ua += 0x7fffu + ((ua >> 16) & 1u);
    u32 ub = __float_as_uint(b); ub += 0x7fffu + ((ub >> 16) & 1u);
    return (ua >> 16) | (ub & 0xffff0000u);
}

// ---------------------------------------------------------------------------
// Kernel 1: fold DWT into conv weights (registers only, no LDS/barriers).
// Thread (t = lane) builds Wd[·][t] in 84 regs; wave-uniform cw reads.
// Emits bf16 in MFMA B-fragment order:
//   Wf[(((s*8+nt)*128 + kb)*64 + fq*16 + fr)*8 + jj],
//   kb = t*2 + (hw>>5), fq = (hw>>3)&3, jj = hw&7, nt = n>>4, fr = n&15.
// One block per (s,n). Wd order: lo3(14) | hi1(35) | hi2(21) | hi3(14).
// ---------------------------------------------------------------------------
__global__ __launch_bounds__(256, 1) void fold_w(const float* __restrict__ cw,
                                                 u16* __restrict__ Wf) {
    const int tid = threadIdx.x;
    const int t   = tid & 63;
    const int wq  = __builtin_amdgcn_readfirstlane((int)(tid >> 6)); // wave 0..3

    float wd[84], lo1[35], lo2[21];
#pragma unroll
    for (int i = 0; i < 35; ++i) {                // level 1: N=64, reflect 6
        float sl = 0.f, sh = 0.f;
#pragma unroll
        for (int k = 0; k < 8; ++k) {
            int s = 2 * i + k - 6;
            if (s < 0) s = -s;
            if (s >= 64) s = 126 - s;
            float xv = (s == t) ? 1.0f : 0.0f;
            sl += xv * GL[k]; sh += xv * GH[k];
        }
        lo1[i] = sl;
        wd[14 + i] = sh;
    }
#pragma unroll
    for (int i = 0; i < 21; ++i) {                // level 2: N=35 (+1 zero)
        float sl = 0.f, sh = 0.f;
#pragma unroll
        for (int k = 0; k < 8; ++k) {
            int s = 2 * i + k - 6;
            if (s < 0) s = -s;
            if (s >= 36) s = 70 - s;
            float xv = (s >= 35) ? 0.0f : lo1[s];
            sl += xv * GL[k]; sh += xv * GH[k];
        }
        lo2[i] = sl;
        wd[49 + i] = sh;
    }
#pragma unroll
    for (int i = 0; i < 14; ++i) {                // level 3: N=21 (+1 zero)
        float sl = 0.f, sh = 0.f;
#pragma unroll
        for (int k = 0; k < 8; ++k) {
            int s = 2 * i + k - 6;
            if (s < 0) s = -s;
            if (s >= 22) s = 42 - s;
            float xv = (s >= 21) ? 0.0f : lo2[s];
            sl += xv * GL[k]; sh += xv * GH[k];
        }
        wd[i] = sl;
        wd[70 + i] = sh;
    }

    const int sk = blockIdx.x;                    // s*128 + n
    const float* cwp = cw + (size_t)sk * (84 * 64) + wq * 16;  // wave-uniform
    float acc[16];
#pragma unroll
    for (int j = 0; j < 16; ++j) acc[j] = 0.f;
#pragma unroll
    for (int tau = 0; tau < 84; ++tau) {
#pragma unroll
        for (int j = 0; j < 16; ++j)
            acc[j] += cwp[tau * 64 + j] * wd[tau];
    }

    const int s  = sk >> 7;
    const int n  = sk & 127;
    const int nt = n >> 4;
    const int fr = n & 15;
#pragma unroll
    for (int h8 = 0; h8 < 2; ++h8) {
        const int hw0 = wq * 16 + h8 * 8;
        const int kb  = t * 2 + (hw0 >> 5);
        const int fq  = (hw0 >> 3) & 3;
        union { u16 h[8]; u32 w2[4]; } pk;
#pragma unroll
        for (int j = 0; j < 8; ++j) pk.h[j] = f32_bf16(acc[h8 * 8 + j]);
        const size_t idx =
            ((((size_t)(s * 8 + nt)) * 128 + kb) * 64 + fq * 16 + fr) * 8;
        *reinterpret_cast<u32*>(&Wf[idx])     = pk.w2[0];
        *reinterpret_cast<u32*>(&Wf[idx + 2]) = pk.w2[1];
        *reinterpret_cast<u32*>(&Wf[idx + 4]) = pk.w2[2];
        *reinterpret_cast<u32*>(&Wf[idx + 6]) = pk.w2[3];
    }
}

// ---------------------------------------------------------------------------
// Kernel 2: DRAM-streaming MFMA GEMM, barrier-free (per-wave LDS transposer).
// Wave (ksid, s, mt): 32(m) x 128(n) tile over K-slice of 4096/KS.
// K-chunks of 128 floats: 16 global loads, each 2 rows x 512B CONTIGUOUS
// (lane = k-offset). fp32->bf16 pack, XOR-swizzled per-wave LDS (8KB),
// fragment ds_read_b128, 64 MFMA/chunk. No __syncthreads anywhere.
// ---------------------------------------------------------------------------
template <int KS>
__global__ __launch_bounds__(256, 2) void gemm4(const float* __restrict__ X,
                                                const u16* __restrict__ Wf,
                                                float* __restrict__ P) {
    const int tid  = threadIdx.x;
    const int lane = tid & 63;
    const int gw   = blockIdx.x * 4 + (tid >> 6);
    const int ksid = gw >> 8;          // 0..KS-1
    const int s    = (gw >> 6) & 3;    // subwindow
    const int mt   = gw & 63;          // m-tile (32 rows)
    const int fr   = lane & 15;
    const int fq   = lane >> 4;
    const int sub  = lane >> 5;        // 0/1  (row parity for staging)
    const int col  = lane & 31;        // k-offset group (col*4 floats)

    constexpr int NCH = 32 / KS;       // K-chunks of 128 per slice

    __shared__ __align__(16) u16 lds[4][32 * 128];
    u16* L = lds[tid >> 6];

    // staging addresses: load r covers rows {2r, 2r+1}, 512B contiguous each
    const float* xrow = X + (size_t)(mt * 32 + sub) * 16384 + s * 4096
                          + (size_t)ksid * (4096 / KS) + col * 4;
    // LDS write index (u16): row*128 + ((cw ^ (row&15))<<3) + (col&1)*4
    // B pointer: nt stride 65536, kb stride 512 (u16)
    const u16* wg = Wf + ((size_t)(s * 8) * 128 + ksid * (128 / KS)) * 512 + lane * 8;

    f32x4 acc0[8], acc1[8];
#pragma unroll
    for (int nt = 0; nt < 8; ++nt) {
        acc0[nt] = (f32x4){0.f, 0.f, 0.f, 0.f};
        acc1[nt] = (f32x4){0.f, 0.f, 0.f, 0.f};
    }

    f32x4 stag[16];
#pragma unroll
    for (int r = 0; r < 16; ++r)
        stag[r] = *reinterpret_cast<const f32x4*>(xrow + (size_t)(2 * r) * 16384);

    for (int c = 0; c < NCH; ++c) {
        // ---- write chunk c to this wave's LDS slice (bf16, swizzled) ----
#pragma unroll
        for (int r = 0; r < 16; ++r) {
            const int row = 2 * r + sub;
            const u32 p0 = pack2_bf16(stag[r].x, stag[r].y);
            const u32 p1 = pack2_bf16(stag[r].z, stag[r].w);
            const int idx = row * 128 + (((col >> 1) ^ (row & 15)) << 3) + (col & 1) * 4;
            u32* d = reinterpret_cast<u32*>(&L[idx]);
            d[0] = p0; d[1] = p1;
        }
        // ---- prefetch chunk c+1 ----
        if (c + 1 < NCH) {
#pragma unroll
            for (int r = 0; r < 16; ++r)
                stag[r] = *reinterpret_cast<const f32x4*>(
                    xrow + (size_t)(2 * r) * 16384 + (size_t)(c + 1) * 128);
        }
        // ---- MFMA on chunk c ----
        const u16* wc = wg + (size_t)(c * 4) * 512;
#pragma unroll
        for (int kb = 0; kb < 4; ++kb) {
            const int ch = (kb << 2) + fq;
            bf16x8 a0 = *reinterpret_cast<const bf16x8*>(
                &L[fr * 128 + ((ch ^ fr) << 3)]);
            bf16x8 a1 = *reinterpret_cast<const bf16x8*>(
                &L[(16 + fr) * 128 + ((ch ^ fr) << 3)]);
            const u16* wb = wc + (size_t)kb * 512;
#pragma unroll
            for (int nt = 0; nt < 8; ++nt) {
                bf16x8 b = *reinterpret_cast<const bf16x8*>(wb + (size_t)nt * 65536);
                acc0[nt] = __builtin_amdgcn_mfma_f32_16x16x32_bf16(a0, b, acc0[nt], 0, 0, 0);
                acc1[nt] = __builtin_amdgcn_mfma_f32_16x16x32_bf16(a1, b, acc1[nt], 0, 0, 0);
            }
        }
    }

    // partials: P[ksid][mt*32 + h*16 + fq*4 + r][s*128 + nt*16 + fr]
    float* pg = P + (size_t)ksid * (2048 * 512) + (size_t)(mt * 32) * 512 + s * 128 + fr;
#pragma unroll
    for (int nt = 0; nt < 8; ++nt)
#pragma unroll
        for (int r = 0; r < 4; ++r) {
            __builtin_nontemporal_store(acc0[nt][r], pg + (size_t)(fq * 4 + r) * 512 + nt * 16);
            __builtin_nontemporal_store(acc1[nt][r], pg + (size_t)(16 + fq * 4 + r) * 512 + nt * 16);
        }
}

// ---------------------------------------------------------------------------
// Kernel 3: reduce K-slices, add bias, leaky-ReLU.
// ---------------------------------------------------------------------------
__global__ __launch_bounds__(256) void reduce_k(const float* __restrict__ P,
                                                const float* __restrict__ bias,
                                                float* __restrict__ out, int nks) {
    const int t = blockIdx.x * 256 + threadIdx.x;     // 0..262143
    const size_t base = (size_t)t * 4;
    f32x4 sum = {0.f, 0.f, 0.f, 0.f};
    for (int k = 0; k < nks; ++k) {
        f32x4 v = __builtin_nontemporal_load(
            reinterpret_cast<const f32x4*>(P + (size_t)k * (2048 * 512) + base));
        sum += v;
    }
    const f32x4 b = *reinterpret_cast<const f32x4*>(bias + (base & 511));
    f32x4 o = sum + b;
    o.x = o.x > 0.f ? o.x : 0.01f * o.x;
    o.y = o.y > 0.f ? o.y : 0.01f * o.y;
    o.z = o.z > 0.f ? o.z : 0.01f * o.z;
    o.w = o.w > 0.f ? o.w : 0.01f * o.w;
    __builtin_nontemporal_store(o, reinterpret_cast<f32x4*>(out + base));
}

// ---------------------------------------------------------------------------
extern "C" void kernel_launch(void* const* d_in, const int* in_sizes, int n_in,
                              void* d_out, int out_size, void* d_ws, size_t ws_size,
                              hipStream_t stream) {
    const float* x  = (const float*)d_in[0];   // [2048,1,256,8,8] fp32
    const float* cw = (const float*)d_in[1];   // [4,128,84,8,8]   fp32
    const float* cb = (const float*)d_in[2];   // [4,128]          fp32
    float* out = (float*)d_out;                // [2048,512]       fp32

    u16*   Wf = (u16*)d_ws;                              // 4 MiB, B-fragment order
    float* P  = (float*)((char*)d_ws + (4u << 20));      // KS * 4 MiB partials

    const size_t MN = (size_t)2048 * 512 * 4;            // 4 MiB per K-slice
    const int ks = (ws_size >= (4u << 20) + 4 * MN) ? 4 : 1;

    fold_w<<<512, 256, 0, stream>>>(cw, Wf);
    if (ks == 4) gemm4<4><<<256, 256, 0, stream>>>(x, Wf, P);
    else         gemm4<1><<< 64, 256, 0, stream>>>(x, Wf, P);
    reduce_k<<<1024, 256, 0, stream>>>(P, cb, out, ks);
}